// Round 2
// baseline (306.104 us; speedup 1.0000x reference)
//
#include <hip/hip_runtime.h>
#include <hip/hip_bf16.h>

constexpr int kB  = 16;
constexpr int kT  = 4096;
constexpr int kD  = 512;
constexpr int kC  = 10;
constexpr int kFW = 100;
constexpr int kKW = 2 * kFW + 1;   // 201
constexpr int kKP = 544;           // GEMM K: 512 (W_enc) + 10 (W_att) + 22 zeros

typedef __attribute__((ext_vector_type(8))) short short8_t;  // 8 bf16 (4 VGPRs)
typedef __attribute__((ext_vector_type(4))) float float4_t;  // MFMA acc

__device__ __forceinline__ float tanh_fast(float x) {
  float ax = fabsf(x);
  float z  = __expf(-2.0f * ax);
  float r  = (1.0f - z) / (1.0f + z);
  return copysignf(r, x);
}

__device__ __forceinline__ short f2bf(float x) {  // RNE f32->bf16 (scalar)
  unsigned u = __float_as_uint(x);
  u += 0x7fffu + ((u >> 16) & 1u);
  return (short)(u >> 16);
}

__device__ __forceinline__ unsigned pk2(float lo, float hi) {  // packed cvt
  __hip_bfloat162 h = __float22bfloat162_rn(make_float2(lo, hi));
  union { __hip_bfloat162 h2; unsigned u; } cv; cv.h2 = h; return cv.u;
}

__device__ __forceinline__ float bf2f(short s) {
  return __uint_as_float(((unsigned)(unsigned short)s) << 16);
}

__device__ __forceinline__ void glds16(const void* g, void* l) {
  __builtin_amdgcn_global_load_lds(
      (const __attribute__((address_space(1))) void*)g,
      (__attribute__((address_space(3))) void*)l, 16, 0, 0);
}

// ---- fused prep: dec_bias | pack_w | conv | convert (independent block ranges)
__global__ __launch_bounds__(256) void prep_kernel(
    const float* __restrict__ query, const float* __restrict__ W_dec,
    const float* __restrict__ b_enc, float* __restrict__ bias,
    const float* __restrict__ W_enc, const float* __restrict__ W_att,
    short* __restrict__ Wbf,
    const float* __restrict__ att_prev, const float* __restrict__ W_conv,
    const float* __restrict__ value, const int* __restrict__ lens,
    short* __restrict__ Abf) {
  __shared__ float ap[256 + 2 * kFW];
  __shared__ float wc[kC * kKW];
  int blk = blockIdx.x;
  int tid = threadIdx.x;

  if (blk < 2048) {
    // dec_bias: bias[b,d] = b_enc[d] + query[b,:] . W_dec[d,:]
    int gw   = (blk * 256 + tid) >> 6;
    int lane = tid & 63;
    int b = gw >> 9, d = gw & (kD - 1);
    const float* q = query + (size_t)b * kD;
    const float* w = W_dec + (size_t)d * kD;
    float s = 0.f;
#pragma unroll
    for (int k0 = 0; k0 < kD; k0 += 256) {
      float4 qa = *(const float4*)(q + k0 + lane * 4);
      float4 wa = *(const float4*)(w + k0 + lane * 4);
      s += qa.x * wa.x + qa.y * wa.y + qa.z * wa.z + qa.w * wa.w;
    }
#pragma unroll
    for (int off = 32; off > 0; off >>= 1) s += __shfl_down(s, off, 64);
    if (lane == 0) bias[gw] = b_enc[d] + s;
  } else if (blk < 2048 + 512) {
    // pack_w: Wbf[d][544] = [W_enc row | W_att row | zeros]
    int d = blk - 2048;
    for (int c = tid; c < kKP; c += 256) {
      float v = 0.f;
      if (c < kD)           v = W_enc[(size_t)d * kD + c];
      else if (c < kD + kC) v = W_att[(size_t)d * kC + (c - kD)];
      Wbf[(size_t)d * kKP + c] = f2bf(v);
    }
  } else if (blk < 2048 + 512 + 256) {
    // conv: channels -> Abf[b][t][512:544] (10 real + 22 zeros)
    int lin = blk - 2560;
    int b = lin >> 4, t0 = (lin & 15) * 256;
    for (int i = tid; i < kC * kKW; i += 256) wc[i] = W_conv[i];
    for (int i = tid; i < 256 + 2 * kFW; i += 256) {
      int p = t0 - kFW + i;
      ap[i] = (p >= 0 && p < kT) ? att_prev[(size_t)b * kT + p] : 0.f;
    }
    __syncthreads();
    float acc[kC];
#pragma unroll
    for (int c = 0; c < kC; ++c) acc[c] = 0.f;
    for (int j = 0; j < kKW; ++j) {
      float a = ap[tid + j];
#pragma unroll
      for (int c = 0; c < kC; ++c) acc[c] += a * wc[c * kKW + j];
    }
    unsigned ow[16];
#pragma unroll
    for (int i = 0; i < 5; ++i) ow[i] = pk2(acc[2 * i], acc[2 * i + 1]);
#pragma unroll
    for (int i = 5; i < 16; ++i) ow[i] = 0u;
    uint4* out = (uint4*)(Abf + ((size_t)b * kT + t0 + tid) * kKP + kD);
#pragma unroll
    for (int i = 0; i < 4; ++i)
      out[i] = make_uint4(ow[4 * i], ow[4 * i + 1], ow[4 * i + 2], ow[4 * i + 3]);
  } else {
    // convert: Abf[b][t][0:512] = bf16(value), 64 t-rows per block
    int lin = blk - 2816;
    int b = lin >> 6, t0 = (lin & 63) * 64;
    if (t0 >= lens[b]) return;
    const float* src = value + ((size_t)b * kT + t0) * kD;
    short* dst = Abf + ((size_t)b * kT + t0) * kKP;
#pragma unroll
    for (int i = 0; i < 16; ++i) {
      int c = tid + i * 256;
      int row = c >> 6, col = (c & 63) * 8;
      float4 f0 = *(const float4*)(src + (size_t)row * kD + col);
      float4 f1 = *(const float4*)(src + (size_t)row * kD + col + 4);
      uint4 o;
      o.x = pk2(f0.x, f0.y); o.y = pk2(f0.z, f0.w);
      o.z = pk2(f1.x, f1.y); o.w = pk2(f1.z, f1.w);
      *(uint4*)(dst + (size_t)row * kKP + col) = o;
    }
  }
}

// e_kernel v2: 256x128 block tile, 4 waves of 128x64 (MFMA:ds_read ratio 2.67
// vs 2.0 for 64x64 -- LDS feed 96 B/cyc < 128 B/cyc ceiling), uniform BK=32
// x17 steps, 3-buffer LDS rotation (72 KB, 2 blocks/CU), depth-2 prefetch with
// counted vmcnt + raw barriers (loads stay in flight across barriers).
__global__ __launch_bounds__(256, 2) void e_kernel(
    const short* __restrict__ Abf, const short* __restrict__ Wbf,
    const float* __restrict__ bias, const float* __restrict__ w_g,
    const int* __restrict__ lens, float* __restrict__ e_part) {
  __shared__ short As[3 * 256 * 32];   // 3 x 16 KB
  __shared__ short Bs[3 * 128 * 32];   // 3 x 8 KB

  int tid = threadIdx.x;
  // XCD-balanced swizzle: m-tiles round-robin over XCDs; the 4 n-blocks of one
  // m-tile stay on one XCD (L2 A-reuse). grid = 1024 = 256 m-tiles x 4 n.
  int L    = blockIdx.x;
  int xcd  = L & 7;
  int slot = L >> 3;
  int bn   = slot & 3;
  int mt   = (slot >> 2) * 8 + xcd;    // 0..255
  int b  = mt >> 4;
  int t0 = (mt & 15) * 256;
  if (t0 >= lens[b]) return;           // masked tile: partials never read
  int n0 = bn * 128;

  int w    = tid >> 6;
  int lane = tid & 63;
  int nl   = lane & 15;
  int quad = lane >> 4;
  int wm = w >> 1, wn = w & 1;         // wave tile: rows wm*128, cols wn*64

  // staging: lane l -> LDS row base+(l>>2), chunk (l&3); source chunk
  // kc4 = (l&3)^((l>>2)&3) so the linear deposit lands XOR-swizzled.
  int r4  = lane >> 2;
  int kc4 = (lane & 3) ^ (r4 & 3);
  const short* asrc = Abf + ((size_t)(b * kT + t0) + w * 64 + r4) * kKP + kc4 * 8;
  const short* bsrc = Wbf + (size_t)(n0 + w * 32 + r4) * kKP + kc4 * 8;

  // frag reads: [row][32] view, row stride 64B; chunk co = quad ^ (row&3)
  int co = (quad ^ (nl & 3)) * 8;

  float4_t acc[8][4] = {};

#define STAGE(bi, k0)                                                   \
  do {                                                                  \
    short* ad = As + (bi) * 8192 + (w * 64) * 32;                       \
    short* bd = Bs + (bi) * 4096 + (w * 32) * 32;                       \
    const short* as_ = asrc + (k0);                                     \
    const short* bs_ = bsrc + (k0);                                     \
    glds16(as_,                ad);                                     \
    glds16(as_ + 16 * kKP,     ad + 16 * 32);                           \
    glds16(as_ + 32 * kKP,     ad + 32 * 32);                           \
    glds16(as_ + 48 * kKP,     ad + 48 * 32);                           \
    glds16(bs_,                bd);                                     \
    glds16(bs_ + 16 * kKP,     bd + 16 * 32);                           \
  } while (0)

  STAGE(0, 0);
  STAGE(1, 32);
  int cur = 0, stg = 2;
#pragma unroll 1
  for (int kk = 0; kk < 17; ++kk) {
    if (kk < 15) STAGE(stg, (kk + 2) * 32);
    // counted drains: keep the 2 prefetched steps (12 loads) in flight.
    if (kk < 15)      asm volatile("s_waitcnt vmcnt(12)" ::: "memory");
    else if (kk < 16) asm volatile("s_waitcnt vmcnt(6)" ::: "memory");
    else              asm volatile("s_waitcnt vmcnt(0)" ::: "memory");
    __builtin_amdgcn_s_barrier();          // all waves' deposits for cur visible
    __builtin_amdgcn_sched_barrier(0);     // pin: no ds_read hoists above barrier
    const short* aB = As + cur * 8192 + (wm * 128 + nl) * 32 + co;
    const short* bB = Bs + cur * 4096 + (wn * 64 + nl) * 32 + co;
    short8_t a_frag[8], b_frag[4];
#pragma unroll
    for (int i = 0; i < 8; ++i) a_frag[i] = *(const short8_t*)(aB + i * 512);
#pragma unroll
    for (int j = 0; j < 4; ++j) b_frag[j] = *(const short8_t*)(bB + j * 512);
    __builtin_amdgcn_s_setprio(1);
#pragma unroll
    for (int i = 0; i < 8; ++i)
#pragma unroll
      for (int j = 0; j < 4; ++j)
        acc[i][j] = __builtin_amdgcn_mfma_f32_16x16x32_bf16(
            a_frag[i], b_frag[j], acc[i][j], 0, 0, 0);
    __builtin_amdgcn_s_setprio(0);
    __builtin_amdgcn_sched_barrier(0);     // pin: reads stay above barrier
    __builtin_amdgcn_s_barrier();          // reads of cur done -> overwritable
    cur = (cur == 2) ? 0 : cur + 1;
    stg = (stg == 2) ? 0 : stg + 1;
  }
#undef STAGE

  // epilogue: partial e[t] = sum_d wg[d]*tanh(acc + bias[b,d]); 8 partials/(b,t)
  float bias_r[4], wg_r[4];
#pragma unroll
  for (int j = 0; j < 4; ++j) {
    int d = n0 + wn * 64 + j * 16 + nl;
    bias_r[j] = bias[b * kD + d];
    wg_r[j]   = w_g[d];
  }
  int p = bn * 2 + wn;
  float* ep = e_part + ((size_t)p * kB + b) * kT + t0 + wm * 128;
#pragma unroll
  for (int i = 0; i < 8; ++i) {
#pragma unroll
    for (int r = 0; r < 4; ++r) {
      float s = 0.f;
#pragma unroll
      for (int j = 0; j < 4; ++j)
        s += wg_r[j] * tanh_fast(acc[i][j][r] + bias_r[j]);
      s += __shfl_xor(s, 1, 64);
      s += __shfl_xor(s, 2, 64);
      s += __shfl_xor(s, 4, 64);
      s += __shfl_xor(s, 8, 64);
      if (nl == 0) ep[i * 16 + quad * 4 + r] = s;
    }
  }
}

// softmax stage 1: 256 blocks (b, 256-t chunk): combine 8 partials -> eb,
// chunk max + chunk sum-of-exp -> stats; ch==0 blocks also zero ctx.
__global__ void softmax1_kernel(const float* __restrict__ e_part,
                                const int* __restrict__ lens,
                                float* __restrict__ eb,
                                float* __restrict__ stats,
                                float* __restrict__ ctx) {
  __shared__ float sred[256];
  int b = blockIdx.x >> 4, ch = blockIdx.x & 15;
  int tid = threadIdx.x;
  int len = lens[b];
  if (ch == 0) {                        // zero context accumulators
    ctx[b * kD + tid]       = 0.f;
    ctx[b * kD + 256 + tid] = 0.f;
  }
  int t = ch * 256 + tid;
  float v = -3.0e38f;
  if (t < len) {
    const float* ep = e_part + (size_t)b * kT + t;
    float s = 0.f;
#pragma unroll
    for (int p = 0; p < 8; ++p) s += ep[(size_t)p * kB * kT];
    eb[(size_t)b * kT + t] = s;
    v = s;
  }
  sred[tid] = v; __syncthreads();
  for (int s = 128; s > 0; s >>= 1) {
    if (tid < s) sred[tid] = fmaxf(sred[tid], sred[tid + s]);
    __syncthreads();
  }
  float m = sred[0]; __syncthreads();
  float l = (v > -1.0e38f) ? __expf(2.0f * (v - m)) : 0.f;
  sred[tid] = l; __syncthreads();
  for (int s = 128; s > 0; s >>= 1) {
    if (tid < s) sred[tid] += sred[tid + s];
    __syncthreads();
  }
  if (tid == 0) {
    stats[(b * 16 + ch) * 2]     = m;
    stats[(b * 16 + ch) * 2 + 1] = sred[0];
  }
}

// fused att-write + context: finalize chunk stats per block (redundant, tiny),
// write att for this 64-t chunk, accumulate ctx via LDS + atomics.
__global__ void ctx_att_kernel(const float* __restrict__ eb,
                               const float* __restrict__ stats,
                               const int* __restrict__ lens,
                               const short* __restrict__ Abf,
                               float* __restrict__ att,
                               float* __restrict__ ctx) {
  __shared__ float red[4][kD];
  int b = blockIdx.y;
  int len = lens[b];
  int t0 = blockIdx.x * 64;
  int tid = threadIdx.x;
  float M = -3.0e38f;
#pragma unroll
  for (int p = 0; p < 16; ++p) M = fmaxf(M, stats[(b * 16 + p) * 2]);
  float Lsum = 0.f;
#pragma unroll
  for (int p = 0; p < 16; ++p) {
    float mc = stats[(b * 16 + p) * 2], lc = stats[(b * 16 + p) * 2 + 1];
    if (lc > 0.f) Lsum += lc * __expf(2.0f * (mc - M));
  }
  float inv = 1.0f / Lsum;
  const float* e = eb + (size_t)b * kT + t0;
  if (tid < 64) {
    int t = t0 + tid;
    att[(size_t)b * kT + t] = (t < len) ? __expf(2.0f * (e[tid] - M)) * inv : 0.0f;
  }
  if (t0 >= len) return;
  int w = tid >> 6, lane = tid & 63;
  int tb = w * 16;
  int tmax = min(16, len - t0 - tb);
  float a[8] = {0.f, 0.f, 0.f, 0.f, 0.f, 0.f, 0.f, 0.f};
  const short* vp = Abf + ((size_t)b * kT + t0 + tb) * kKP + lane * 8;
  for (int t = 0; t < tmax; ++t) {
    float wt = __expf(2.0f * (e[tb + t] - M)) * inv;
    short8_t v = *(const short8_t*)(vp + (size_t)t * kKP);
#pragma unroll
    for (int i = 0; i < 8; ++i) a[i] += wt * bf2f(v[i]);
  }
#pragma unroll
  for (int i = 0; i < 8; ++i) red[w][lane * 8 + i] = a[i];
  __syncthreads();
  for (int col = tid; col < kD; col += 256) {
    float s = red[0][col] + red[1][col] + red[2][col] + red[3][col];
    atomicAdd(&ctx[b * kD + col], s);
  }
}

extern "C" void kernel_launch(void* const* d_in, const int* in_sizes, int n_in,
                              void* d_out, int out_size, void* d_ws, size_t ws_size,
                              hipStream_t stream) {
  const float* value    = (const float*)d_in[0];
  const float* query    = (const float*)d_in[1];
  const int*   lens     = (const int*)  d_in[2];
  const float* att_prev = (const float*)d_in[3];
  const float* W_enc    = (const float*)d_in[4];
  const float* b_enc    = (const float*)d_in[5];
  const float* W_dec    = (const float*)d_in[6];
  const float* W_att    = (const float*)d_in[7];
  const float* W_conv   = (const float*)d_in[8];
  const float* w_g      = (const float*)d_in[9];
  // d_in[10] = b_g : unused (softmax shift-invariant)

  float* ws     = (float*)d_ws;
  float* e_part = ws;                                      // 8*kB*kT   (2 MB)
  float* eb     = e_part + (size_t)8 * kB * kT;            // kB*kT     (256 KB)
  float* stats  = eb + (size_t)kB * kT;                    // 512 floats
  float* bias   = stats + 512;                             // kB*kD     (32 KB)
  short* Wbf    = (short*)(bias + (size_t)kB * kD);        // kD*kKP    (557 KB)
  short* Abf    = Wbf + (size_t)kD * kKP;                  // kB*kT*kKP (71.3 MB)
  float* ctx = (float*)d_out;
  float* att = ctx + (size_t)kB * kD;

  prep_kernel<<<3840, 256, 0, stream>>>(query, W_dec, b_enc, bias,
                                        W_enc, W_att, Wbf,
                                        att_prev, W_conv, value, lens, Abf);
  e_kernel<<<1024, 256, 0, stream>>>(Abf, Wbf, bias, w_g, lens, e_part);
  softmax1_kernel<<<kB * 16, 256, 0, stream>>>(e_part, lens, eb, stats, ctx);
  ctx_att_kernel<<<dim3(kT / 64, kB), 256, 0, stream>>>(eb, stats, lens, Abf, att, ctx);
}

// Round 3
// 293.042 us; speedup vs baseline: 1.0446x; 1.0446x over previous
//
#include <hip/hip_runtime.h>
#include <hip/hip_bf16.h>

constexpr int kB  = 16;
constexpr int kT  = 4096;
constexpr int kD  = 512;
constexpr int kC  = 10;
constexpr int kFW = 100;
constexpr int kKW = 2 * kFW + 1;   // 201
constexpr int kKP = 576;           // GEMM K: 512 (W_enc) + 10 (W_att) + 54 zeros (9x BK64)

typedef __attribute__((ext_vector_type(8))) short short8_t;  // 8 bf16 (4 VGPRs)
typedef __attribute__((ext_vector_type(4))) float float4_t;  // MFMA acc

__device__ __forceinline__ float tanh_fast(float x) {
  float ax = fabsf(x);
  float z  = __expf(-2.0f * ax);
  float r  = (1.0f - z) / (1.0f + z);
  return copysignf(r, x);
}

__device__ __forceinline__ short f2bf(float x) {  // RNE f32->bf16 (scalar)
  unsigned u = __float_as_uint(x);
  u += 0x7fffu + ((u >> 16) & 1u);
  return (short)(u >> 16);
}

__device__ __forceinline__ unsigned pk2(float lo, float hi) {  // packed cvt
  __hip_bfloat162 h = __float22bfloat162_rn(make_float2(lo, hi));
  union { __hip_bfloat162 h2; unsigned u; } cv; cv.h2 = h; return cv.u;
}

__device__ __forceinline__ float bf2f(short s) {
  return __uint_as_float(((unsigned)(unsigned short)s) << 16);
}

__device__ __forceinline__ void glds16(const void* g, void* l) {
  __builtin_amdgcn_global_load_lds(
      (const __attribute__((address_space(1))) void*)g,
      (__attribute__((address_space(3))) void*)l, 16, 0, 0);
}

// ---- fused prep: dec_bias | pack_w | conv | convert (independent block ranges)
__global__ __launch_bounds__(256) void prep_kernel(
    const float* __restrict__ query, const float* __restrict__ W_dec,
    const float* __restrict__ b_enc, float* __restrict__ bias,
    const float* __restrict__ W_enc, const float* __restrict__ W_att,
    short* __restrict__ Wbf,
    const float* __restrict__ att_prev, const float* __restrict__ W_conv,
    const float* __restrict__ value, const int* __restrict__ lens,
    short* __restrict__ Abf) {
  __shared__ float ap[256 + 2 * kFW];
  __shared__ float wc[kC * kKW];
  int blk = blockIdx.x;
  int tid = threadIdx.x;

  if (blk < 2048) {
    // dec_bias: bias[b,d] = b_enc[d] + query[b,:] . W_dec[d,:]
    int gw   = (blk * 256 + tid) >> 6;
    int lane = tid & 63;
    int b = gw >> 9, d = gw & (kD - 1);
    const float* q = query + (size_t)b * kD;
    const float* w = W_dec + (size_t)d * kD;
    float s = 0.f;
#pragma unroll
    for (int k0 = 0; k0 < kD; k0 += 256) {
      float4 qa = *(const float4*)(q + k0 + lane * 4);
      float4 wa = *(const float4*)(w + k0 + lane * 4);
      s += qa.x * wa.x + qa.y * wa.y + qa.z * wa.z + qa.w * wa.w;
    }
#pragma unroll
    for (int off = 32; off > 0; off >>= 1) s += __shfl_down(s, off, 64);
    if (lane == 0) bias[gw] = b_enc[d] + s;
  } else if (blk < 2048 + 512) {
    // pack_w: Wbf[d][576] = [W_enc row | W_att row | zeros]
    int d = blk - 2048;
    for (int c = tid; c < kKP; c += 256) {
      float v = 0.f;
      if (c < kD)           v = W_enc[(size_t)d * kD + c];
      else if (c < kD + kC) v = W_att[(size_t)d * kC + (c - kD)];
      Wbf[(size_t)d * kKP + c] = f2bf(v);
    }
  } else if (blk < 2048 + 512 + 256) {
    // conv: channels -> Abf[b][t][512:576] (10 real + 54 zeros)
    int lin = blk - 2560;
    int b = lin >> 4, t0 = (lin & 15) * 256;
    for (int i = tid; i < kC * kKW; i += 256) wc[i] = W_conv[i];
    for (int i = tid; i < 256 + 2 * kFW; i += 256) {
      int p = t0 - kFW + i;
      ap[i] = (p >= 0 && p < kT) ? att_prev[(size_t)b * kT + p] : 0.f;
    }
    __syncthreads();
    float acc[kC];
#pragma unroll
    for (int c = 0; c < kC; ++c) acc[c] = 0.f;
    for (int j = 0; j < kKW; ++j) {
      float a = ap[tid + j];
#pragma unroll
      for (int c = 0; c < kC; ++c) acc[c] += a * wc[c * kKW + j];
    }
    unsigned ow[32];
#pragma unroll
    for (int i = 0; i < 5; ++i) ow[i] = pk2(acc[2 * i], acc[2 * i + 1]);
#pragma unroll
    for (int i = 5; i < 32; ++i) ow[i] = 0u;
    uint4* out = (uint4*)(Abf + ((size_t)b * kT + t0 + tid) * kKP + kD);
#pragma unroll
    for (int i = 0; i < 8; ++i)
      out[i] = make_uint4(ow[4 * i], ow[4 * i + 1], ow[4 * i + 2], ow[4 * i + 3]);
  } else {
    // convert: Abf[b][t][0:512] = bf16(value), 64 t-rows per block
    int lin = blk - 2816;
    int b = lin >> 6, t0 = (lin & 63) * 64;
    if (t0 >= lens[b]) return;
    const float* src = value + ((size_t)b * kT + t0) * kD;
    short* dst = Abf + ((size_t)b * kT + t0) * kKP;
#pragma unroll
    for (int i = 0; i < 16; ++i) {
      int c = tid + i * 256;
      int row = c >> 6, col = (c & 63) * 8;
      float4 f0 = *(const float4*)(src + (size_t)row * kD + col);
      float4 f1 = *(const float4*)(src + (size_t)row * kD + col + 4);
      uint4 o;
      o.x = pk2(f0.x, f0.y); o.y = pk2(f0.z, f0.w);
      o.z = pk2(f1.x, f1.y); o.w = pk2(f1.z, f1.w);
      *(uint4*)(dst + (size_t)row * kKP + col) = o;
    }
  }
}

// e_kernel v3: m201-style 8-phase. 256x256 block tile, 8 waves (2M x 4N,
// wave-tile 128x64 -> 384 B LDS-read/MFMA), BK=64 x 9 tiles (K=576 padded),
// 2-slot dbuf (128 KB LDS), 1 half-tile staged per phase, counted vmcnt:
// vmcnt(4)@p1 retires incoming A1; vmcnt(2)@p3 retires next tile's A0,B0,B1
// (A1 stays in flight across the tile boundary). asm s_barrier with "memory"
// clobber = compile-time fence (no ds_read hoists) without HW counter drain.
__global__ __launch_bounds__(512, 2) void e_kernel(
    const short* __restrict__ Abf, const short* __restrict__ Wbf,
    const float* __restrict__ bias, const float* __restrict__ w_g,
    const int* __restrict__ lens, float* __restrict__ e_part) {
  __shared__ short As[2 * 256 * 64];   // 64 KB: 2 slots x [256 rows][64 k]
  __shared__ short Bs[2 * 256 * 64];   // 64 KB

  int tid  = threadIdx.x;
  // XCD-contiguous bijective map (512 = 8*64): the 2 n-blocks of one m-tile
  // land on the same XCD (L2 A-panel reuse).
  int L    = blockIdx.x;
  int g    = (L & 7) * 64 + (L >> 3);
  int mt   = g >> 1;                   // 0..255
  int bn   = g & 1;
  int b  = mt >> 4;
  int t0 = (mt & 15) * 256;
  if (t0 >= lens[b]) return;           // masked tile: partials never read
  int n0 = bn * 256;

  int w    = tid >> 6;                 // 0..7
  int lane = tid & 63;
  int nl   = lane & 15;
  int quad = lane >> 4;
  int wm = w >> 2, wn = w & 3;         // wave tile: rows wm*128, cols wn*64

  // staging: per-wave 1 KB/glds; lane l -> dest row w*8+(l>>3), chunk l&7;
  // source chunk pre-XOR'd so the linear deposit lands swizzled.
  int srow = w * 8 + (lane >> 3);
  int sc   = (lane & 7) ^ ((lane >> 3) & 7);
  const short* aS = Abf + ((size_t)(b * kT + t0) + srow) * kKP + sc * 8;
  const short* bS = Wbf + ((size_t)(n0 + srow)) * kKP + sc * 8;

  // frag reads: chunk' = (ks*4+quad) ^ (row&7), row&7 == nl&7
  int x7  = nl & 7;
  int co0 = ((0 * 4 + quad) ^ x7) * 8;
  int co1 = ((1 * 4 + quad) ^ x7) * 8;

  short8_t aF[8], bF0[4], bF1[4];
  float4_t acc[8][4] = {};

#define BARM() asm volatile("s_barrier" ::: "memory")
#define VMW(n) asm volatile("s_waitcnt vmcnt(" #n ")" ::: "memory")

#define STAGE_A(NXT, H, TAU)                                                \
  do {                                                                      \
    glds16(aS + (size_t)((H) * 128) * kKP + (TAU) * 64,                     \
           &As[(NXT) * 16384 + ((H) * 128 + w * 8) * 64]);                  \
    glds16(aS + (size_t)((H) * 128 + 64) * kKP + (TAU) * 64,                \
           &As[(NXT) * 16384 + ((H) * 128 + 64 + w * 8) * 64]);             \
  } while (0)
#define STAGE_B(NXT, H, TAU)                                                \
  do {                                                                      \
    glds16(bS + (size_t)((H) * 128) * kKP + (TAU) * 64,                     \
           &Bs[(NXT) * 16384 + ((H) * 128 + w * 8) * 64]);                  \
    glds16(bS + (size_t)((H) * 128 + 64) * kKP + (TAU) * 64,                \
           &Bs[(NXT) * 16384 + ((H) * 128 + 64 + w * 8) * 64]);             \
  } while (0)

#define LOAD_A(CUR, MH)                                                     \
  do {                                                                      \
    const short* p_ = &As[(CUR) * 16384 + (wm * 128 + (MH) * 64 + nl) * 64];\
    _Pragma("unroll") for (int fi = 0; fi < 4; ++fi) {                      \
      aF[fi * 2 + 0] = *(const short8_t*)(p_ + fi * 1024 + co0);            \
      aF[fi * 2 + 1] = *(const short8_t*)(p_ + fi * 1024 + co1);            \
    }                                                                       \
  } while (0)
#define LOAD_B(CUR, NH, DST)                                                \
  do {                                                                      \
    const short* p_ = &Bs[(CUR) * 16384 + (wn * 64 + (NH) * 32 + nl) * 64]; \
    _Pragma("unroll") for (int fj = 0; fj < 2; ++fj) {                      \
      DST[fj * 2 + 0] = *(const short8_t*)(p_ + fj * 1024 + co0);           \
      DST[fj * 2 + 1] = *(const short8_t*)(p_ + fj * 1024 + co1);           \
    }                                                                       \
  } while (0)

#define MFMA_Q(MH, NH, BFR)                                                 \
  do {                                                                      \
    __builtin_amdgcn_s_setprio(1);                                          \
    _Pragma("unroll") for (int fi = 0; fi < 4; ++fi)                        \
      _Pragma("unroll") for (int fj = 0; fj < 2; ++fj)                      \
        _Pragma("unroll") for (int ks = 0; ks < 2; ++ks)                    \
          acc[(MH) * 4 + fi][(NH) * 2 + fj] =                               \
              __builtin_amdgcn_mfma_f32_16x16x32_bf16(                      \
                  aF[fi * 2 + ks], BFR[fj * 2 + ks],                        \
                  acc[(MH) * 4 + fi][(NH) * 2 + fj], 0, 0, 0);              \
    __builtin_amdgcn_s_setprio(0);                                          \
  } while (0)

#define TILE(CUR, NXT, TAU, DO_STAGE, WAIT1, WAIT3)                         \
  do {                                                                      \
    /* p0: quadrant (0,0) */                                                \
    LOAD_A(CUR, 0); LOAD_B(CUR, 0, bF0);                                    \
    if (DO_STAGE) STAGE_A(NXT, 0, TAU);                                     \
    BARM(); MFMA_Q(0, 0, bF0); BARM();                                      \
    /* p1: quadrant (0,1) */                                                \
    LOAD_B(CUR, 1, bF1);                                                    \
    if (DO_STAGE) STAGE_B(NXT, 0, TAU);                                     \
    WAIT1; BARM(); MFMA_Q(0, 1, bF1); BARM();                               \
    /* p2: quadrant (1,0) */                                                \
    LOAD_A(CUR, 1);                                                         \
    if (DO_STAGE) STAGE_B(NXT, 1, TAU);                                     \
    BARM(); MFMA_Q(1, 0, bF0); BARM();                                      \
    /* p3: quadrant (1,1) */                                                \
    if (DO_STAGE) STAGE_A(NXT, 1, TAU);                                     \
    WAIT3; BARM(); MFMA_Q(1, 1, bF1); BARM();                               \
  } while (0)

  // prologue: stage tile 0 into slot 0, issue order A0,B0,B1,A1;
  // retire A0,B0,B1 (leave A1 in flight -> retired at t0.p1's vmcnt(4)).
  STAGE_A(0, 0, 0); STAGE_B(0, 0, 0); STAGE_B(0, 1, 0); STAGE_A(0, 1, 0);
  VMW(2); BARM();

#pragma unroll 1
  for (int tp = 0; tp < 4; ++tp) {
    TILE(0, 1, 2 * tp + 1, 1, VMW(4), VMW(2));
    TILE(1, 0, 2 * tp + 2, 1, VMW(4), VMW(2));
  }
  // epilogue tile 8 (slot 0, staged during t=7; no prefetch)
  TILE(0, 1, 0, 0, VMW(0), (void)0);

#undef TILE
#undef MFMA_Q
#undef LOAD_B
#undef LOAD_A
#undef STAGE_B
#undef STAGE_A
#undef VMW
#undef BARM

  // epilogue: partial e[t] = sum_d wg[d]*tanh(acc + bias[b,d]); 8 partials/(b,t)
  float bias_r[4], wg_r[4];
#pragma unroll
  for (int j = 0; j < 4; ++j) {
    int d = n0 + wn * 64 + j * 16 + nl;
    bias_r[j] = bias[b * kD + d];
    wg_r[j]   = w_g[d];
  }
  int p = bn * 4 + wn;
  float* ep = e_part + ((size_t)p * kB + b) * kT + t0 + wm * 128;
#pragma unroll
  for (int i = 0; i < 8; ++i) {
#pragma unroll
    for (int r = 0; r < 4; ++r) {
      float s = 0.f;
#pragma unroll
      for (int j = 0; j < 4; ++j)
        s += wg_r[j] * tanh_fast(acc[i][j][r] + bias_r[j]);
      s += __shfl_xor(s, 1, 64);
      s += __shfl_xor(s, 2, 64);
      s += __shfl_xor(s, 4, 64);
      s += __shfl_xor(s, 8, 64);
      if (nl == 0) ep[i * 16 + quad * 4 + r] = s;
    }
  }
}

// softmax stage 1: 256 blocks (b, 256-t chunk): combine 8 partials -> eb,
// chunk max + chunk sum-of-exp -> stats; ch==0 blocks also zero ctx.
__global__ void softmax1_kernel(const float* __restrict__ e_part,
                                const int* __restrict__ lens,
                                float* __restrict__ eb,
                                float* __restrict__ stats,
                                float* __restrict__ ctx) {
  __shared__ float sred[256];
  int b = blockIdx.x >> 4, ch = blockIdx.x & 15;
  int tid = threadIdx.x;
  int len = lens[b];
  if (ch == 0) {                        // zero context accumulators
    ctx[b * kD + tid]       = 0.f;
    ctx[b * kD + 256 + tid] = 0.f;
  }
  int t = ch * 256 + tid;
  float v = -3.0e38f;
  if (t < len) {
    const float* ep = e_part + (size_t)b * kT + t;
    float s = 0.f;
#pragma unroll
    for (int p = 0; p < 8; ++p) s += ep[(size_t)p * kB * kT];
    eb[(size_t)b * kT + t] = s;
    v = s;
  }
  sred[tid] = v; __syncthreads();
  for (int s = 128; s > 0; s >>= 1) {
    if (tid < s) sred[tid] = fmaxf(sred[tid], sred[tid + s]);
    __syncthreads();
  }
  float m = sred[0]; __syncthreads();
  float l = (v > -1.0e38f) ? __expf(2.0f * (v - m)) : 0.f;
  sred[tid] = l; __syncthreads();
  for (int s = 128; s > 0; s >>= 1) {
    if (tid < s) sred[tid] += sred[tid + s];
    __syncthreads();
  }
  if (tid == 0) {
    stats[(b * 16 + ch) * 2]     = m;
    stats[(b * 16 + ch) * 2 + 1] = sred[0];
  }
}

// fused att-write + context: finalize chunk stats per block (redundant, tiny),
// write att for this 64-t chunk, accumulate ctx via LDS + atomics.
__global__ void ctx_att_kernel(const float* __restrict__ eb,
                               const float* __restrict__ stats,
                               const int* __restrict__ lens,
                               const short* __restrict__ Abf,
                               float* __restrict__ att,
                               float* __restrict__ ctx) {
  __shared__ float red[4][kD];
  int b = blockIdx.y;
  int len = lens[b];
  int t0 = blockIdx.x * 64;
  int tid = threadIdx.x;
  float M = -3.0e38f;
#pragma unroll
  for (int p = 0; p < 16; ++p) M = fmaxf(M, stats[(b * 16 + p) * 2]);
  float Lsum = 0.f;
#pragma unroll
  for (int p = 0; p < 16; ++p) {
    float mc = stats[(b * 16 + p) * 2], lc = stats[(b * 16 + p) * 2 + 1];
    if (lc > 0.f) Lsum += lc * __expf(2.0f * (mc - M));
  }
  float inv = 1.0f / Lsum;
  const float* e = eb + (size_t)b * kT + t0;
  if (tid < 64) {
    int t = t0 + tid;
    att[(size_t)b * kT + t] = (t < len) ? __expf(2.0f * (e[tid] - M)) * inv : 0.0f;
  }
  if (t0 >= len) return;
  int w = tid >> 6, lane = tid & 63;
  int tb = w * 16;
  int tmax = min(16, len - t0 - tb);
  float a[8] = {0.f, 0.f, 0.f, 0.f, 0.f, 0.f, 0.f, 0.f};
  const short* vp = Abf + ((size_t)b * kT + t0 + tb) * kKP + lane * 8;
  for (int t = 0; t < tmax; ++t) {
    float wt = __expf(2.0f * (e[tb + t] - M)) * inv;
    short8_t v = *(const short8_t*)(vp + (size_t)t * kKP);
#pragma unroll
    for (int i = 0; i < 8; ++i) a[i] += wt * bf2f(v[i]);
  }
#pragma unroll
  for (int i = 0; i < 8; ++i) red[w][lane * 8 + i] = a[i];
  __syncthreads();
  for (int col = tid; col < kD; col += 256) {
    float s = red[0][col] + red[1][col] + red[2][col] + red[3][col];
    atomicAdd(&ctx[b * kD + col], s);
  }
}

extern "C" void kernel_launch(void* const* d_in, const int* in_sizes, int n_in,
                              void* d_out, int out_size, void* d_ws, size_t ws_size,
                              hipStream_t stream) {
  const float* value    = (const float*)d_in[0];
  const float* query    = (const float*)d_in[1];
  const int*   lens     = (const int*)  d_in[2];
  const float* att_prev = (const float*)d_in[3];
  const float* W_enc    = (const float*)d_in[4];
  const float* b_enc    = (const float*)d_in[5];
  const float* W_dec    = (const float*)d_in[6];
  const float* W_att    = (const float*)d_in[7];
  const float* W_conv   = (const float*)d_in[8];
  const float* w_g      = (const float*)d_in[9];
  // d_in[10] = b_g : unused (softmax shift-invariant)

  float* ws     = (float*)d_ws;
  float* e_part = ws;                                      // 8*kB*kT   (2 MB)
  float* eb     = e_part + (size_t)8 * kB * kT;            // kB*kT     (256 KB)
  float* stats  = eb + (size_t)kB * kT;                    // 512 floats
  float* bias   = stats + 512;                             // kB*kD     (32 KB)
  short* Wbf    = (short*)(bias + (size_t)kB * kD);        // kD*kKP    (576 KB)
  short* Abf    = Wbf + (size_t)kD * kKP;                  // kB*kT*kKP (75.5 MB)
  float* ctx = (float*)d_out;
  float* att = ctx + (size_t)kB * kD;

  prep_kernel<<<3840, 256, 0, stream>>>(query, W_dec, b_enc, bias,
                                        W_enc, W_att, Wbf,
                                        att_prev, W_conv, value, lens, Abf);
  e_kernel<<<512, 512, 0, stream>>>(Abf, Wbf, bias, w_g, lens, e_part);
  softmax1_kernel<<<kB * 16, 256, 0, stream>>>(e_part, lens, eb, stats, ctx);
  ctx_att_kernel<<<dim3(kT / 64, kB), 256, 0, stream>>>(eb, stats, lens, Abf, att, ctx);
}